// Round 1
// baseline (496.301 us; speedup 1.0000x reference)
//
#include <hip/hip_runtime.h>
#include <hip/hip_bf16.h>

#define B_    8
#define N_    2048
#define DIN_  512
#define DOUT_ 256
#define NBUCK 20

typedef __attribute__((ext_vector_type(8))) short  short8;
typedef __attribute__((ext_vector_type(4))) float  floatx4;

__device__ __forceinline__ unsigned short f2b(float f) {
    __hip_bfloat16 h = __float2bfloat16(f);
    unsigned short u;
    __builtin_memcpy(&u, &h, 2);
    return u;
}

// ---------------- conversion kernels ----------------
__global__ __launch_bounds__(256) void cvt_x_kernel(const float* __restrict__ src,
                                                    unsigned short* __restrict__ dst) {
    long long i = ((long long)blockIdx.x * 256 + threadIdx.x) * 8;
    float4 a = *(const float4*)(src + i);
    float4 b = *(const float4*)(src + i + 4);
    uint4 r;
    r.x = f2b(a.x) | ((unsigned)f2b(a.y) << 16);
    r.y = f2b(a.z) | ((unsigned)f2b(a.w) << 16);
    r.z = f2b(b.x) | ((unsigned)f2b(b.y) << 16);
    r.w = f2b(b.z) | ((unsigned)f2b(b.w) << 16);
    *(uint4*)(dst + i) = r;
}

__global__ __launch_bounds__(256) void cvt_w_kernel(const float* __restrict__ wq,
                                                    const float* __restrict__ wk,
                                                    const float* __restrict__ wv,
                                                    unsigned short* __restrict__ dst) {
    int i = (blockIdx.x * 256 + threadIdx.x) * 8;  // 0 .. 393216-8
    const float* src;
    if (i < 131072)      src = wq + i;
    else if (i < 262144) src = wk + (i - 131072);
    else                 src = wv + (i - 262144);
    float4 a = *(const float4*)(src);
    float4 b = *(const float4*)(src + 4);
    uint4 r;
    r.x = f2b(a.x) | ((unsigned)f2b(a.y) << 16);
    r.y = f2b(a.z) | ((unsigned)f2b(a.w) << 16);
    r.z = f2b(b.x) | ((unsigned)f2b(b.y) << 16);
    r.w = f2b(b.z) | ((unsigned)f2b(b.w) << 16);
    *(uint4*)(dst + i) = r;
}

// ---------------- QKV GEMM ----------------
// grid (256, 12): x = 64-row block of the 16384 rows, y = 64-col block of 768 outputs
// cols 0..255 -> q, 256..511 -> k, 512..767 -> v (stored transposed per batch)
__global__ __launch_bounds__(256) void qkv_kernel(
    const unsigned short* __restrict__ xb, const unsigned short* __restrict__ wb,
    const float* __restrict__ bq, const float* __restrict__ bk, const float* __restrict__ bv,
    unsigned short* __restrict__ q, unsigned short* __restrict__ k,
    unsigned short* __restrict__ vT) {
    __shared__ unsigned short tlds[64][68];  // v transpose staging (o x n), +4 pad
    const int tid  = threadIdx.x;
    const int wave = tid >> 6, lane = tid & 63, quad = lane >> 4, l16 = lane & 15;
    const int rowBlk = blockIdx.x, colBlk = blockIdx.y;
    const int row0 = rowBlk * 64 + wave * 16;
    const int col0 = colBlk * 64;

    floatx4 acc[4];
#pragma unroll
    for (int t = 0; t < 4; ++t) acc[t] = (floatx4){0.f, 0.f, 0.f, 0.f};

    const unsigned short* arow = xb + (size_t)(row0 + l16) * DIN_ + quad * 8;
    const unsigned short* brow = wb + (size_t)(col0 + l16) * DIN_ + quad * 8;
#pragma unroll 4
    for (int kc = 0; kc < DIN_; kc += 32) {
        short8 af = *(const short8*)(arow + kc);
#pragma unroll
        for (int ct = 0; ct < 4; ++ct) {
            short8 bf = *(const short8*)(brow + (size_t)ct * 16 * DIN_ + kc);
            acc[ct] = __builtin_amdgcn_mfma_f32_16x16x32_bf16(af, bf, acc[ct], 0, 0, 0);
        }
    }

    if (colBlk < 8) {  // q / k, row-major [16384,256]
#pragma unroll
        for (int ct = 0; ct < 4; ++ct) {
            int col = col0 + ct * 16 + l16;
            unsigned short* dst = (col < 256) ? q : k;
            float bias = (col < 256) ? bq[col] : bk[col - 256];
            int c = col & 255;
#pragma unroll
            for (int r = 0; r < 4; ++r) {
                int row = row0 + quad * 4 + r;
                dst[(size_t)row * DOUT_ + c] = f2b(acc[ct][r] + bias);
            }
        }
    } else {  // v: transpose through LDS -> vT[b][o][n]
        int ocol0 = col0 - 512;
#pragma unroll
        for (int ct = 0; ct < 4; ++ct) {
            float bias = bv[ocol0 + ct * 16 + l16];
#pragma unroll
            for (int r = 0; r < 4; ++r)
                tlds[ct * 16 + l16][wave * 16 + quad * 4 + r] = f2b(acc[ct][r] + bias);
        }
        __syncthreads();
        int bb = (rowBlk * 64) >> 11;   // batch
        int nb = (rowBlk * 64) & 2047;  // n within batch
#pragma unroll
        for (int it = 0; it < 4; ++it) {
            int idx = it * 256 + tid;
            int o = idx >> 4, seg = idx & 15;
            uint2 val = *(const uint2*)&tlds[o][seg * 4];
            *(uint2*)(vT + ((size_t)bb * DOUT_ + ocol0 + o) * N_ + nb + seg * 4) = val;
        }
    }
}

// ---------------- fused gated flash attention + final projection ----------------
// grid 256: b = g&7 (XCD-affine), nblk = g>>3. 4 waves x 16 q-rows = 64 rows/WG.
__global__ __launch_bounds__(256) void attn_kernel(
    const unsigned short* __restrict__ q, const unsigned short* __restrict__ k,
    const unsigned short* __restrict__ vT, const int* __restrict__ pr,
    const float* __restrict__ rank_emb, const float* __restrict__ rank_w,
    const float* __restrict__ Ws, const float* __restrict__ bs,
    float* __restrict__ out) {
    const int g = blockIdx.x;
    const int b = g & 7;
    const int nblk = g >> 3;
    const int tid = threadIdx.x, wave = tid >> 6, lane = tid & 63;
    const int quad = lane >> 4, l16 = lane & 15;
    const int n0 = nblk * 64 + wave * 16;

    __shared__ float gtab[NBUCK];
    __shared__ unsigned short plds[4][16][40];  // per-wave P tile [n][m(32)+pad]

    if (tid < NBUCK) {
        float rw = rank_w[0];
        gtab[tid] = 1.f / (1.f + __expf(-rw * rank_emb[tid]));
    }
    __syncthreads();

    const unsigned short* qb = q + (size_t)b * N_ * DOUT_;
    const unsigned short* kb = k + (size_t)b * N_ * DOUT_;
    const unsigned short* vb = vT + (size_t)b * DOUT_ * N_;
    const int* prb = pr + b * N_;

    short8 qf[8];
#pragma unroll
    for (int c = 0; c < 8; ++c)
        qf[c] = *(const short8*)(qb + (size_t)(n0 + l16) * DOUT_ + c * 32 + quad * 8);

    int prn[4];
#pragma unroll
    for (int r = 0; r < 4; ++r) prn[r] = prb[n0 + quad * 4 + r];

    floatx4 o_acc[16];
#pragma unroll
    for (int t = 0; t < 16; ++t) o_acc[t] = (floatx4){0.f, 0.f, 0.f, 0.f};
    float m_run[4] = {-1e30f, -1e30f, -1e30f, -1e30f};
    float l_run[4] = {0.f, 0.f, 0.f, 0.f};

    const float scale = 0.0625f;  // 1/sqrt(256)

    for (int m0 = 0; m0 < N_; m0 += 32) {
        // ---- S = Q K^T for 32 m-columns (two 16-wide halves) ----
        floatx4 s[2];
        s[0] = (floatx4){0.f, 0.f, 0.f, 0.f};
        s[1] = (floatx4){0.f, 0.f, 0.f, 0.f};
#pragma unroll
        for (int h = 0; h < 2; ++h) {
            const unsigned short* krow = kb + (size_t)(m0 + h * 16 + l16) * DOUT_ + quad * 8;
#pragma unroll
            for (int c = 0; c < 8; ++c) {
                short8 kf = *(const short8*)(krow + c * 32);
                s[h] = __builtin_amdgcn_mfma_f32_16x16x32_bf16(qf[c], kf, s[h], 0, 0, 0);
            }
        }
        // ---- gate + scale ----
        int prm0 = prb[m0 + l16];
        int prm1 = prb[m0 + 16 + l16];
        float tmax[4];
#pragma unroll
        for (int r = 0; r < 4; ++r) {
            int d0 = abs(prn[r] - prm0);
            int d1 = abs(prn[r] - prm1);
            float g0 = gtab[min(d0 / 5, NBUCK - 1)];
            float g1 = gtab[min(d1 / 5, NBUCK - 1)];
            s[0][r] = s[0][r] * scale * g0;
            s[1][r] = s[1][r] * scale * g1;
            tmax[r] = fmaxf(s[0][r], s[1][r]);
        }
#pragma unroll
        for (int off = 1; off < 16; off <<= 1) {
#pragma unroll
            for (int r = 0; r < 4; ++r)
                tmax[r] = fmaxf(tmax[r], __shfl_xor(tmax[r], off, 64));
        }
        // ---- online softmax update ----
        float alpha[4], p0[4], p1[4], psum[4];
#pragma unroll
        for (int r = 0; r < 4; ++r) {
            float mn = fmaxf(m_run[r], tmax[r]);
            alpha[r] = __expf(m_run[r] - mn);
            m_run[r] = mn;
            p0[r] = __expf(s[0][r] - mn);
            p1[r] = __expf(s[1][r] - mn);
            psum[r] = p0[r] + p1[r];
        }
#pragma unroll
        for (int off = 1; off < 16; off <<= 1) {
#pragma unroll
            for (int r = 0; r < 4; ++r)
                psum[r] += __shfl_xor(psum[r], off, 64);
        }
#pragma unroll
        for (int r = 0; r < 4; ++r) l_run[r] = l_run[r] * alpha[r] + psum[r];
#pragma unroll
        for (int t = 0; t < 16; ++t) {
#pragma unroll
            for (int r = 0; r < 4; ++r) o_acc[t][r] *= alpha[r];
        }
        // ---- P -> LDS (C-layout -> A-operand layout round trip) ----
#pragma unroll
        for (int r = 0; r < 4; ++r) {
            plds[wave][quad * 4 + r][l16]      = f2b(p0[r]);
            plds[wave][quad * 4 + r][16 + l16] = f2b(p1[r]);
        }
        __syncthreads();
        short8 pa = *(const short8*)(&plds[wave][l16][quad * 8]);
        // ---- O += P V ----
#pragma unroll
        for (int t = 0; t < 16; ++t) {
            short8 vf = *(const short8*)(vb + (size_t)(t * 16 + l16) * N_ + m0 + quad * 8);
            o_acc[t] = __builtin_amdgcn_mfma_f32_16x16x32_bf16(pa, vf, o_acc[t], 0, 0, 0);
        }
        __syncthreads();
    }

    // ---- epilogue: winner = sigmoid((O/l) . Ws + bs) ----
    float wdot[4] = {0.f, 0.f, 0.f, 0.f};
#pragma unroll
    for (int t = 0; t < 16; ++t) {
        float w = Ws[t * 16 + l16];
#pragma unroll
        for (int r = 0; r < 4; ++r) wdot[r] += o_acc[t][r] * w;
    }
#pragma unroll
    for (int off = 1; off < 16; off <<= 1) {
#pragma unroll
        for (int r = 0; r < 4; ++r) wdot[r] += __shfl_xor(wdot[r], off, 64);
    }
    if (l16 == 0) {
        float bsv = bs[0];
#pragma unroll
        for (int r = 0; r < 4; ++r) {
            float logit = wdot[r] / l_run[r] + bsv;
            out[(size_t)b * N_ + n0 + quad * 4 + r] = 1.f / (1.f + __expf(-logit));
        }
    }
}

// ---------------- launch ----------------
extern "C" void kernel_launch(void* const* d_in, const int* in_sizes, int n_in,
                              void* d_out, int out_size, void* d_ws, size_t ws_size,
                              hipStream_t stream) {
    const float* x   = (const float*)d_in[0];
    const int*   pr  = (const int*)d_in[1];   // harness delivers integers as int32
    const float* Wq  = (const float*)d_in[2];
    const float* bq  = (const float*)d_in[3];
    const float* Wk  = (const float*)d_in[4];
    const float* bk  = (const float*)d_in[5];
    const float* Wv  = (const float*)d_in[6];
    const float* bv  = (const float*)d_in[7];
    const float* Ws  = (const float*)d_in[8];
    const float* bs  = (const float*)d_in[9];
    const float* remb = (const float*)d_in[10];
    const float* rw   = (const float*)d_in[11];
    float* out = (float*)d_out;

    char* ws = (char*)d_ws;
    unsigned short* xb = (unsigned short*)ws;                       // 16,777,216 B
    unsigned short* wb = (unsigned short*)(ws + 16777216);          //    786,432 B
    unsigned short* q  = (unsigned short*)(ws + 17563648);          //  8,388,608 B
    unsigned short* kk = (unsigned short*)(ws + 25952256);          //  8,388,608 B
    unsigned short* vT = (unsigned short*)(ws + 34340864);          //  8,388,608 B

    hipLaunchKernelGGL(cvt_x_kernel, dim3(4096), dim3(256), 0, stream, x, xb);
    hipLaunchKernelGGL(cvt_w_kernel, dim3(192), dim3(256), 0, stream, Wq, Wk, Wv, wb);
    hipLaunchKernelGGL(qkv_kernel, dim3(256, 12), dim3(256), 0, stream,
                       xb, wb, bq, bk, bv, q, kk, vT);
    hipLaunchKernelGGL(attn_kernel, dim3(256), dim3(256), 0, stream,
                       q, kk, vT, pr, remb, rw, Ws, bs, out);
}

// Round 2
// 473.116 us; speedup vs baseline: 1.0490x; 1.0490x over previous
//
#include <hip/hip_runtime.h>
#include <hip/hip_bf16.h>

#define B_    8
#define N_    2048
#define DIN_  512
#define DOUT_ 256
#define NBUCK 20

typedef __attribute__((ext_vector_type(8))) short  short8;
typedef __attribute__((ext_vector_type(4))) float  floatx4;

__device__ __forceinline__ unsigned short f2b(float f) {
    __hip_bfloat16 h = __float2bfloat16(f);
    unsigned short u;
    __builtin_memcpy(&u, &h, 2);
    return u;
}

// ---------------- conversion kernels ----------------
__global__ __launch_bounds__(256) void cvt_x_kernel(const float* __restrict__ src,
                                                    unsigned short* __restrict__ dst) {
    long long i = ((long long)blockIdx.x * 256 + threadIdx.x) * 8;
    float4 a = *(const float4*)(src + i);
    float4 b = *(const float4*)(src + i + 4);
    uint4 r;
    r.x = f2b(a.x) | ((unsigned)f2b(a.y) << 16);
    r.y = f2b(a.z) | ((unsigned)f2b(a.w) << 16);
    r.z = f2b(b.x) | ((unsigned)f2b(b.y) << 16);
    r.w = f2b(b.z) | ((unsigned)f2b(b.w) << 16);
    *(uint4*)(dst + i) = r;
}

__global__ __launch_bounds__(256) void cvt_w_kernel(const float* __restrict__ wq,
                                                    const float* __restrict__ wk,
                                                    const float* __restrict__ wv,
                                                    unsigned short* __restrict__ dst) {
    int i = (blockIdx.x * 256 + threadIdx.x) * 8;  // 0 .. 393216-8
    const float* src;
    if (i < 131072)      src = wq + i;
    else if (i < 262144) src = wk + (i - 131072);
    else                 src = wv + (i - 262144);
    float4 a = *(const float4*)(src);
    float4 b = *(const float4*)(src + 4);
    uint4 r;
    r.x = f2b(a.x) | ((unsigned)f2b(a.y) << 16);
    r.y = f2b(a.z) | ((unsigned)f2b(a.w) << 16);
    r.z = f2b(b.x) | ((unsigned)f2b(b.y) << 16);
    r.w = f2b(b.z) | ((unsigned)f2b(b.w) << 16);
    *(uint4*)(dst + i) = r;
}

// ---------------- QKV GEMM ----------------
__global__ __launch_bounds__(256) void qkv_kernel(
    const unsigned short* __restrict__ xb, const unsigned short* __restrict__ wb,
    const float* __restrict__ bq, const float* __restrict__ bk, const float* __restrict__ bv,
    unsigned short* __restrict__ q, unsigned short* __restrict__ k,
    unsigned short* __restrict__ vT) {
    __shared__ unsigned short tlds[64][68];  // v transpose staging (o x n), +4 pad
    const int tid  = threadIdx.x;
    const int wave = tid >> 6, lane = tid & 63, quad = lane >> 4, l16 = lane & 15;
    const int rowBlk = blockIdx.x, colBlk = blockIdx.y;
    const int row0 = rowBlk * 64 + wave * 16;
    const int col0 = colBlk * 64;

    floatx4 acc[4];
#pragma unroll
    for (int t = 0; t < 4; ++t) acc[t] = (floatx4){0.f, 0.f, 0.f, 0.f};

    const unsigned short* arow = xb + (size_t)(row0 + l16) * DIN_ + quad * 8;
    const unsigned short* brow = wb + (size_t)(col0 + l16) * DIN_ + quad * 8;
#pragma unroll 4
    for (int kc = 0; kc < DIN_; kc += 32) {
        short8 af = *(const short8*)(arow + kc);
#pragma unroll
        for (int ct = 0; ct < 4; ++ct) {
            short8 bf = *(const short8*)(brow + (size_t)ct * 16 * DIN_ + kc);
            acc[ct] = __builtin_amdgcn_mfma_f32_16x16x32_bf16(af, bf, acc[ct], 0, 0, 0);
        }
    }

    if (colBlk < 8) {  // q / k, row-major [16384,256]
#pragma unroll
        for (int ct = 0; ct < 4; ++ct) {
            int col = col0 + ct * 16 + l16;
            unsigned short* dst = (col < 256) ? q : k;
            float bias = (col < 256) ? bq[col] : bk[col - 256];
            int c = col & 255;
#pragma unroll
            for (int r = 0; r < 4; ++r) {
                int row = row0 + quad * 4 + r;
                dst[(size_t)row * DOUT_ + c] = f2b(acc[ct][r] + bias);
            }
        }
    } else {  // v: transpose through LDS -> vT[b][o][n]
        int ocol0 = col0 - 512;
#pragma unroll
        for (int ct = 0; ct < 4; ++ct) {
            float bias = bv[ocol0 + ct * 16 + l16];
#pragma unroll
            for (int r = 0; r < 4; ++r)
                tlds[ct * 16 + l16][wave * 16 + quad * 4 + r] = f2b(acc[ct][r] + bias);
        }
        __syncthreads();
        int bb = (rowBlk * 64) >> 11;   // batch
        int nb = (rowBlk * 64) & 2047;  // n within batch
#pragma unroll
        for (int it = 0; it < 4; ++it) {
            int idx = it * 256 + tid;
            int o = idx >> 4, seg = idx & 15;
            uint2 val = *(const uint2*)&tlds[o][seg * 4];
            *(uint2*)(vT + ((size_t)bb * DOUT_ + ocol0 + o) * N_ + nb + seg * 4) = val;
        }
    }
}

// ---------------- fused gated flash attention + final projection ----------------
// grid 256: b = g&7 (XCD-affine), nblk = g>>3.
// 512 threads = 8 waves = 4 row-groups x 2 m-splits. Each wave: 16 q-rows,
// 1024 KV columns in steps of 64. No inner-loop barriers (per-wave LDS tiles).
// Splits combine through LDS on 3 scalars per row (wdot, l, m).
__global__ __launch_bounds__(512, 2) void attn_kernel(
    const unsigned short* __restrict__ q, const unsigned short* __restrict__ k,
    const unsigned short* __restrict__ vT, const int* __restrict__ pr,
    const float* __restrict__ rank_emb, const float* __restrict__ rank_w,
    const float* __restrict__ Ws, const float* __restrict__ bs,
    float* __restrict__ out) {
    const int g = blockIdx.x;
    const int b = g & 7;
    const int nblk = g >> 3;
    const int tid = threadIdx.x, wave = tid >> 6, lane = tid & 63;
    const int quad = lane >> 4, l16 = lane & 15;
    const int rg = wave & 3;        // row group 0..3
    const int sp = wave >> 2;       // m-split 0..1
    const int n0 = nblk * 64 + rg * 16;

    __shared__ float gtab[NBUCK];                 // sigmoid-gate * scale
    __shared__ unsigned short plds[8][16][72];    // per-wave P tile [n][m(64)+pad]
    __shared__ float wdL[2][64], lL[2][64], mL[2][64];

    if (tid < NBUCK) {
        float rw = rank_w[0];
        gtab[tid] = 0.0625f / (1.f + __expf(-rw * rank_emb[tid]));  // scale folded in
    }
    __syncthreads();

    const unsigned short* qb = q + (size_t)b * N_ * DOUT_;
    const unsigned short* kb = k + (size_t)b * N_ * DOUT_;
    const unsigned short* vb = vT + (size_t)b * DOUT_ * N_;
    const int* prb = pr + b * N_;

    short8 qf[8];
#pragma unroll
    for (int c = 0; c < 8; ++c)
        qf[c] = *(const short8*)(qb + (size_t)(n0 + l16) * DOUT_ + c * 32 + quad * 8);

    int prn[4];
#pragma unroll
    for (int r = 0; r < 4; ++r) prn[r] = prb[n0 + quad * 4 + r];

    floatx4 o_acc[16];
#pragma unroll
    for (int t = 0; t < 16; ++t) o_acc[t] = (floatx4){0.f, 0.f, 0.f, 0.f};
    float m_run[4] = {-1e30f, -1e30f, -1e30f, -1e30f};
    float l_run[4] = {0.f, 0.f, 0.f, 0.f};

    const int mbeg = sp * 1024;
    for (int m0 = mbeg; m0 < mbeg + 1024; m0 += 64) {
        // ---- S = Q K^T for 64 m-columns (four 16-wide halves) ----
        floatx4 s[4];
#pragma unroll
        for (int h = 0; h < 4; ++h) s[h] = (floatx4){0.f, 0.f, 0.f, 0.f};
#pragma unroll
        for (int h = 0; h < 4; ++h) {
            const unsigned short* krow = kb + (size_t)(m0 + h * 16 + l16) * DOUT_ + quad * 8;
#pragma unroll
            for (int c = 0; c < 8; ++c) {
                short8 kf = *(const short8*)(krow + c * 32);
                s[h] = __builtin_amdgcn_mfma_f32_16x16x32_bf16(qf[c], kf, s[h], 0, 0, 0);
            }
        }
        // ---- gate (scale folded in) + row max ----
        int prm[4];
#pragma unroll
        for (int h = 0; h < 4; ++h) prm[h] = prb[m0 + h * 16 + l16];
        float tmax[4];
#pragma unroll
        for (int r = 0; r < 4; ++r) {
#pragma unroll
            for (int h = 0; h < 4; ++h) {
                int d = abs(prn[r] - prm[h]);
                s[h][r] *= gtab[min(d / 5, NBUCK - 1)];
            }
            tmax[r] = fmaxf(fmaxf(s[0][r], s[1][r]), fmaxf(s[2][r], s[3][r]));
        }
#pragma unroll
        for (int off = 1; off < 16; off <<= 1) {
#pragma unroll
            for (int r = 0; r < 4; ++r)
                tmax[r] = fmaxf(tmax[r], __shfl_xor(tmax[r], off, 64));
        }
        // ---- online softmax update ----
        float alpha[4], p[4][4], psum[4];
#pragma unroll
        for (int r = 0; r < 4; ++r) {
            float mn = fmaxf(m_run[r], tmax[r]);
            alpha[r] = __expf(m_run[r] - mn);
            m_run[r] = mn;
            psum[r] = 0.f;
#pragma unroll
            for (int h = 0; h < 4; ++h) {
                p[h][r] = __expf(s[h][r] - mn);
                psum[r] += p[h][r];
            }
        }
#pragma unroll
        for (int off = 1; off < 16; off <<= 1) {
#pragma unroll
            for (int r = 0; r < 4; ++r)
                psum[r] += __shfl_xor(psum[r], off, 64);
        }
#pragma unroll
        for (int r = 0; r < 4; ++r) l_run[r] = l_run[r] * alpha[r] + psum[r];
#pragma unroll
        for (int t = 0; t < 16; ++t) {
#pragma unroll
            for (int r = 0; r < 4; ++r) o_acc[t][r] *= alpha[r];
        }
        // ---- P -> LDS (C-layout -> A-operand layout), per-wave tile, no barrier ----
#pragma unroll
        for (int h = 0; h < 4; ++h) {
#pragma unroll
            for (int r = 0; r < 4; ++r)
                plds[wave][quad * 4 + r][h * 16 + l16] = f2b(p[h][r]);
        }
        short8 pa0 = *(const short8*)(&plds[wave][l16][quad * 8]);
        short8 pa1 = *(const short8*)(&plds[wave][l16][32 + quad * 8]);
        // ---- O += P V ----
#pragma unroll
        for (int t = 0; t < 16; ++t) {
            const unsigned short* vrow = vb + (size_t)(t * 16 + l16) * N_ + m0 + quad * 8;
            short8 vf0 = *(const short8*)(vrow);
            short8 vf1 = *(const short8*)(vrow + 32);
            o_acc[t] = __builtin_amdgcn_mfma_f32_16x16x32_bf16(pa0, vf0, o_acc[t], 0, 0, 0);
            o_acc[t] = __builtin_amdgcn_mfma_f32_16x16x32_bf16(pa1, vf1, o_acc[t], 0, 0, 0);
        }
    }

    // ---- per-wave partial epilogue: wdot = O . Ws (unnormalized) ----
    float wdot[4] = {0.f, 0.f, 0.f, 0.f};
#pragma unroll
    for (int t = 0; t < 16; ++t) {
        float w = Ws[t * 16 + l16];
#pragma unroll
        for (int r = 0; r < 4; ++r) wdot[r] += o_acc[t][r] * w;
    }
#pragma unroll
    for (int off = 1; off < 16; off <<= 1) {
#pragma unroll
        for (int r = 0; r < 4; ++r) wdot[r] += __shfl_xor(wdot[r], off, 64);
    }
    if (l16 == 0) {
#pragma unroll
        for (int r = 0; r < 4; ++r) {
            int row = rg * 16 + quad * 4 + r;
            wdL[sp][row] = wdot[r];
            lL[sp][row]  = l_run[r];
            mL[sp][row]  = m_run[r];
        }
    }
    __syncthreads();
    // ---- combine the 2 m-splits, sigmoid, store ----
    if (tid < 64) {
        float m0v = mL[0][tid], m1v = mL[1][tid];
        float M = fmaxf(m0v, m1v);
        float e0 = __expf(m0v - M), e1 = __expf(m1v - M);
        float wd = wdL[0][tid] * e0 + wdL[1][tid] * e1;
        float ll = lL[0][tid] * e0 + lL[1][tid] * e1;
        float logit = wd / ll + bs[0];
        out[(size_t)b * N_ + nblk * 64 + tid] = 1.f / (1.f + __expf(-logit));
    }
}

// ---------------- launch ----------------
extern "C" void kernel_launch(void* const* d_in, const int* in_sizes, int n_in,
                              void* d_out, int out_size, void* d_ws, size_t ws_size,
                              hipStream_t stream) {
    const float* x   = (const float*)d_in[0];
    const int*   pr  = (const int*)d_in[1];
    const float* Wq  = (const float*)d_in[2];
    const float* bq  = (const float*)d_in[3];
    const float* Wk  = (const float*)d_in[4];
    const float* bk  = (const float*)d_in[5];
    const float* Wv  = (const float*)d_in[6];
    const float* bv  = (const float*)d_in[7];
    const float* Ws  = (const float*)d_in[8];
    const float* bs  = (const float*)d_in[9];
    const float* remb = (const float*)d_in[10];
    const float* rw   = (const float*)d_in[11];
    float* out = (float*)d_out;

    char* ws = (char*)d_ws;
    unsigned short* xb = (unsigned short*)ws;                       // 16,777,216 B
    unsigned short* wb = (unsigned short*)(ws + 16777216);          //    786,432 B
    unsigned short* q  = (unsigned short*)(ws + 17563648);          //  8,388,608 B
    unsigned short* kk = (unsigned short*)(ws + 25952256);          //  8,388,608 B
    unsigned short* vT = (unsigned short*)(ws + 34340864);          //  8,388,608 B

    hipLaunchKernelGGL(cvt_x_kernel, dim3(4096), dim3(256), 0, stream, x, xb);
    hipLaunchKernelGGL(cvt_w_kernel, dim3(192), dim3(256), 0, stream, Wq, Wk, Wv, wb);
    hipLaunchKernelGGL(qkv_kernel, dim3(256, 12), dim3(256), 0, stream,
                       xb, wb, bq, bk, bv, q, kk, vT);
    hipLaunchKernelGGL(attn_kernel, dim3(256), dim3(512), 0, stream,
                       q, kk, vT, pr, remb, rw, Ws, bs, out);
}

// Round 3
// 307.373 us; speedup vs baseline: 1.6147x; 1.5392x over previous
//
#include <hip/hip_runtime.h>
#include <hip/hip_bf16.h>

#define B_    8
#define N_    2048
#define DIN_  512
#define DOUT_ 256
#define NBUCK 20

typedef __attribute__((ext_vector_type(8))) short  short8;
typedef __attribute__((ext_vector_type(4))) float  floatx4;

__device__ __forceinline__ unsigned short f2b(float f) {
    __hip_bfloat16 h = __float2bfloat16(f);
    unsigned short u;
    __builtin_memcpy(&u, &h, 2);
    return u;
}

// ---------------- wvs = Wv^T . Ws  (512 floats), bvs = bv . Ws ----------------
__global__ __launch_bounds__(1024) void wvs_kernel(const float* __restrict__ Wv,
                                                   const float* __restrict__ Ws,
                                                   const float* __restrict__ bv,
                                                   float* __restrict__ wvs,
                                                   float* __restrict__ bvs) {
    __shared__ float wsl[DOUT_];
    __shared__ float bvp[DOUT_];
    __shared__ float hsum[DIN_];
    int tid = threadIdx.x;
    if (tid < DOUT_) { wsl[tid] = Ws[tid]; bvp[tid] = Ws[tid] * bv[tid]; }
    __syncthreads();
    int d = tid & 511, half = tid >> 9;
    float s0 = 0.f, s1 = 0.f, s2 = 0.f, s3 = 0.f;
    int o0 = half * 128;
    for (int o = o0; o < o0 + 128; o += 4) {
        s0 += Wv[(size_t)(o + 0) * DIN_ + d] * wsl[o + 0];
        s1 += Wv[(size_t)(o + 1) * DIN_ + d] * wsl[o + 1];
        s2 += Wv[(size_t)(o + 2) * DIN_ + d] * wsl[o + 2];
        s3 += Wv[(size_t)(o + 3) * DIN_ + d] * wsl[o + 3];
    }
    float s = (s0 + s1) + (s2 + s3);
    if (half) hsum[d] = s;
    __syncthreads();
    if (!half) wvs[d] = s + hsum[d];
    if (tid < 64) {
        float bb = bvp[tid] + bvp[tid + 64] + bvp[tid + 128] + bvp[tid + 192];
        for (int off = 1; off < 64; off <<= 1) bb += __shfl_xor(bb, off, 64);
        if (tid == 0) *bvs = bb;
    }
}

// ---------------- x -> bf16, fused vw = x . wvs + bvs ----------------
__global__ __launch_bounds__(256) void cvt_x_kernel(const float* __restrict__ x,
                                                    const float* __restrict__ wvs,
                                                    const float* __restrict__ bvs,
                                                    unsigned short* __restrict__ xb,
                                                    float* __restrict__ vw) {
    int tid = threadIdx.x, wave = tid >> 6, lane = tid & 63;
    int row = blockIdx.x * 4 + wave;
    size_t base = (size_t)row * DIN_ + lane * 8;
    float4 a = *(const float4*)(x + base);
    float4 b = *(const float4*)(x + base + 4);
    float4 wa = *(const float4*)(wvs + lane * 8);
    float4 wb = *(const float4*)(wvs + lane * 8 + 4);
    uint4 r;
    r.x = f2b(a.x) | ((unsigned)f2b(a.y) << 16);
    r.y = f2b(a.z) | ((unsigned)f2b(a.w) << 16);
    r.z = f2b(b.x) | ((unsigned)f2b(b.y) << 16);
    r.w = f2b(b.z) | ((unsigned)f2b(b.w) << 16);
    *(uint4*)(xb + base) = r;
    float d = a.x * wa.x + a.y * wa.y + a.z * wa.z + a.w * wa.w +
              b.x * wb.x + b.y * wb.y + b.z * wb.z + b.w * wb.w;
    for (int off = 1; off < 64; off <<= 1) d += __shfl_xor(d, off, 64);
    if (lane == 0) vw[row] = d + *bvs;
}

// ---------------- Wq,Wk -> bf16 ----------------
__global__ __launch_bounds__(256) void cvt_w_kernel(const float* __restrict__ wq,
                                                    const float* __restrict__ wk,
                                                    unsigned short* __restrict__ dst) {
    int i = (blockIdx.x * 256 + threadIdx.x) * 8;  // 0 .. 262144-8
    const float* src = (i < 131072) ? (wq + i) : (wk + (i - 131072));
    float4 a = *(const float4*)(src);
    float4 b = *(const float4*)(src + 4);
    uint4 r;
    r.x = f2b(a.x) | ((unsigned)f2b(a.y) << 16);
    r.y = f2b(a.z) | ((unsigned)f2b(a.w) << 16);
    r.z = f2b(b.x) | ((unsigned)f2b(b.y) << 16);
    r.w = f2b(b.z) | ((unsigned)f2b(b.w) << 16);
    *(uint4*)(dst + i) = r;
}

// ---------------- Q,K GEMM ----------------
// grid (256, 8): x = 64-row block of 16384 rows, y = 64-col block of 512 outputs
__global__ __launch_bounds__(256) void qkv_kernel(
    const unsigned short* __restrict__ xb, const unsigned short* __restrict__ wb,
    const float* __restrict__ bq, const float* __restrict__ bk,
    unsigned short* __restrict__ q, unsigned short* __restrict__ k) {
    const int tid  = threadIdx.x;
    const int wave = tid >> 6, lane = tid & 63, quad = lane >> 4, l16 = lane & 15;
    const int row0 = blockIdx.x * 64 + wave * 16;
    const int col0 = blockIdx.y * 64;

    floatx4 acc[4];
#pragma unroll
    for (int t = 0; t < 4; ++t) acc[t] = (floatx4){0.f, 0.f, 0.f, 0.f};

    const unsigned short* arow = xb + (size_t)(row0 + l16) * DIN_ + quad * 8;
    const unsigned short* brow = wb + (size_t)(col0 + l16) * DIN_ + quad * 8;
#pragma unroll 4
    for (int kc = 0; kc < DIN_; kc += 32) {
        short8 af = *(const short8*)(arow + kc);
#pragma unroll
        for (int ct = 0; ct < 4; ++ct) {
            short8 bf = *(const short8*)(brow + (size_t)ct * 16 * DIN_ + kc);
            acc[ct] = __builtin_amdgcn_mfma_f32_16x16x32_bf16(af, bf, acc[ct], 0, 0, 0);
        }
    }
#pragma unroll
    for (int ct = 0; ct < 4; ++ct) {
        int col = col0 + ct * 16 + l16;
        unsigned short* dst = (col < 256) ? q : k;
        float bias = (col < 256) ? bq[col] : bk[col - 256];
        int c = col & 255;
#pragma unroll
        for (int r = 0; r < 4; ++r) {
            int row = row0 + quad * 4 + r;
            dst[(size_t)row * DOUT_ + c] = f2b(acc[ct][r] + bias);
        }
    }
}

// ---------------- gated flash attention, scalarized V path ----------------
// grid 256: b = g&7 (XCD-affine), rblk = g>>3 -> 64 q-rows.
// 4 waves: (wave&1) = 32-row half, (wave>>1) = 1024-col m-split.
// Each wave: 32 q-rows (2 A-fragments, each K fragment feeds 2 MFMAs),
// per-lane fixed-max softmax accumulation (l, wd) in fp32 — no inner-loop
// shuffles, barriers, LDS tiles, or PV MFMAs.
__global__ __launch_bounds__(256, 3) void attn_kernel(
    const unsigned short* __restrict__ q, const unsigned short* __restrict__ k,
    const float* __restrict__ vw, const int* __restrict__ pr,
    const float* __restrict__ rank_emb, const float* __restrict__ rank_w,
    const float* __restrict__ bs, const float* __restrict__ bvs,
    float* __restrict__ out) {
    const int g = blockIdx.x;
    const int b = g & 7, rblk = g >> 3;
    const int tid = threadIdx.x, wave = tid >> 6, lane = tid & 63;
    const int quad = lane >> 4, l16 = lane & 15;
    const int rh = wave & 1;   // row half
    const int sp = wave >> 1;  // m split
    const int n0 = rblk * 64 + rh * 32;

    __shared__ float gtab[NBUCK];
    __shared__ float lL[2][64], wdL[2][64];

    if (tid < NBUCK)
        gtab[tid] = 0.0625f / (1.f + __expf(-rank_w[0] * rank_emb[tid]));
    __syncthreads();

    const unsigned short* qb = q + (size_t)b * N_ * DOUT_;
    const unsigned short* kb = k + (size_t)b * N_ * DOUT_;
    const float* vwb = vw + b * N_;
    const int* prb = pr + b * N_;

    short8 qf[2][8];
#pragma unroll
    for (int a = 0; a < 2; ++a)
#pragma unroll
        for (int c = 0; c < 8; ++c)
            qf[a][c] = *(const short8*)(qb + (size_t)(n0 + a * 16 + l16) * DOUT_ + c * 32 + quad * 8);

    int prn[2][4];
#pragma unroll
    for (int a = 0; a < 2; ++a)
#pragma unroll
        for (int r = 0; r < 4; ++r) prn[a][r] = prb[n0 + a * 16 + quad * 4 + r];

    float lacc[2][4], wacc[2][4];
#pragma unroll
    for (int a = 0; a < 2; ++a)
#pragma unroll
        for (int r = 0; r < 4; ++r) { lacc[a][r] = 0.f; wacc[a][r] = 0.f; }

    const int mbeg = sp * 1024;
    for (int m0 = mbeg; m0 < mbeg + 1024; m0 += 32) {
        floatx4 s[2][2];
#pragma unroll
        for (int a = 0; a < 2; ++a)
#pragma unroll
            for (int h = 0; h < 2; ++h) s[a][h] = (floatx4){0.f, 0.f, 0.f, 0.f};
#pragma unroll
        for (int h = 0; h < 2; ++h) {
            const unsigned short* krow = kb + (size_t)(m0 + h * 16 + l16) * DOUT_ + quad * 8;
#pragma unroll
            for (int c = 0; c < 8; ++c) {
                short8 kf = *(const short8*)(krow + c * 32);
                s[0][h] = __builtin_amdgcn_mfma_f32_16x16x32_bf16(qf[0][c], kf, s[0][h], 0, 0, 0);
                s[1][h] = __builtin_amdgcn_mfma_f32_16x16x32_bf16(qf[1][c], kf, s[1][h], 0, 0, 0);
            }
        }
#pragma unroll
        for (int h = 0; h < 2; ++h) {
            int col = m0 + h * 16 + l16;
            int prm = prb[col];
            float vwv = vwb[col];
#pragma unroll
            for (int a = 0; a < 2; ++a)
#pragma unroll
                for (int r = 0; r < 4; ++r) {
                    int d = abs(prn[a][r] - prm);
                    float p = __expf(s[a][h][r] * gtab[min(d / 5, NBUCK - 1)]);
                    lacc[a][r] += p;
                    wacc[a][r] += p * vwv;
                }
        }
    }

    // merge partial (l, wd) across the 16 column-lanes
#pragma unroll
    for (int off = 1; off < 16; off <<= 1) {
#pragma unroll
        for (int a = 0; a < 2; ++a)
#pragma unroll
            for (int r = 0; r < 4; ++r) {
                lacc[a][r] += __shfl_xor(lacc[a][r], off, 64);
                wacc[a][r] += __shfl_xor(wacc[a][r], off, 64);
            }
    }
    if (l16 == 0) {
#pragma unroll
        for (int a = 0; a < 2; ++a)
#pragma unroll
            for (int r = 0; r < 4; ++r) {
                int row = rh * 32 + a * 16 + quad * 4 + r;
                lL[sp][row]  = lacc[a][r];
                wdL[sp][row] = wacc[a][r];
            }
    }
    __syncthreads();
    if (tid < 64) {
        float l  = lL[0][tid] + lL[1][tid];
        float wd = wdL[0][tid] + wdL[1][tid];
        float logit = wd / l + *bvs + bs[0];
        out[(size_t)b * N_ + rblk * 64 + tid] = 1.f / (1.f + __expf(-logit));
    }
}

// ---------------- launch ----------------
extern "C" void kernel_launch(void* const* d_in, const int* in_sizes, int n_in,
                              void* d_out, int out_size, void* d_ws, size_t ws_size,
                              hipStream_t stream) {
    const float* x   = (const float*)d_in[0];
    const int*   pr  = (const int*)d_in[1];
    const float* Wq  = (const float*)d_in[2];
    const float* bq  = (const float*)d_in[3];
    const float* Wk  = (const float*)d_in[4];
    const float* bk  = (const float*)d_in[5];
    const float* Wv  = (const float*)d_in[6];
    const float* bv  = (const float*)d_in[7];
    const float* Ws  = (const float*)d_in[8];
    const float* bs  = (const float*)d_in[9];
    const float* remb = (const float*)d_in[10];
    const float* rw   = (const float*)d_in[11];
    float* out = (float*)d_out;

    char* ws = (char*)d_ws;
    unsigned short* xb  = (unsigned short*)ws;                    // 16,777,216 B
    unsigned short* wb  = (unsigned short*)(ws + 16777216);       //    524,288 B
    unsigned short* q   = (unsigned short*)(ws + 17301504);       //  8,388,608 B
    unsigned short* kk  = (unsigned short*)(ws + 25690112);       //  8,388,608 B
    float*          vwp = (float*)(ws + 34078720);                //     65,536 B
    float*          wvs = (float*)(ws + 34144256);                //      2,048 B
    float*          bvs = (float*)(ws + 34146304);                //          4 B

    hipLaunchKernelGGL(wvs_kernel, dim3(1), dim3(1024), 0, stream, Wv, Ws, bv, wvs, bvs);
    hipLaunchKernelGGL(cvt_x_kernel, dim3(4096), dim3(256), 0, stream, x, wvs, bvs, xb, vwp);
    hipLaunchKernelGGL(cvt_w_kernel, dim3(128), dim3(256), 0, stream, Wq, Wk, wb);
    hipLaunchKernelGGL(qkv_kernel, dim3(256, 8), dim3(256), 0, stream,
                       xb, wb, bq, bk, q, kk);
    hipLaunchKernelGGL(attn_kernel, dim3(256), dim3(256), 0, stream,
                       q, kk, vwp, pr, remb, rw, bs, bvs, out);
}

// Round 4
// 232.561 us; speedup vs baseline: 2.1341x; 1.3217x over previous
//
#include <hip/hip_runtime.h>
#include <hip/hip_bf16.h>

#define B_    8
#define N_    2048
#define DIN_  512
#define DOUT_ 256
#define NBUCK 20

typedef __attribute__((ext_vector_type(8))) short  short8;
typedef __attribute__((ext_vector_type(4))) float  floatx4;

__device__ __forceinline__ unsigned short f2b(float f) {
    __hip_bfloat16 h = __float2bfloat16(f);
    unsigned short u;
    __builtin_memcpy(&u, &h, 2);
    return u;
}

// ---------------- wvs = Wv^T . Ws (512 floats), bvs = bv . Ws ----------------
// 4 blocks x 128 threads, one d-column per thread (coalesced over d per o-row).
__global__ __launch_bounds__(128) void wvs_kernel(const float* __restrict__ Wv,
                                                  const float* __restrict__ Ws,
                                                  const float* __restrict__ bv,
                                                  float* __restrict__ wvs,
                                                  float* __restrict__ bvs) {
    __shared__ float wsl[DOUT_];
    int tid = threadIdx.x;
    wsl[tid] = Ws[tid];
    wsl[tid + 128] = Ws[tid + 128];
    __syncthreads();
    int d = blockIdx.x * 128 + tid;
    float s = 0.f;
#pragma unroll 8
    for (int o = 0; o < DOUT_; ++o) s += Wv[(size_t)o * DIN_ + d] * wsl[o];
    wvs[d] = s;
    if (blockIdx.x == 0 && tid < 64) {
        float bb = wsl[tid] * bv[tid] + wsl[tid + 64] * bv[tid + 64] +
                   wsl[tid + 128] * bv[tid + 128] + wsl[tid + 192] * bv[tid + 192];
        for (int off = 1; off < 64; off <<= 1) bb += __shfl_xor(bb, off, 64);
        if (tid == 0) *bvs = bb;
    }
}

// ---------------- x -> bf16, fused vw = x . wvs + bvs ----------------
__global__ __launch_bounds__(256) void cvt_x_kernel(const float* __restrict__ x,
                                                    const float* __restrict__ wvs,
                                                    const float* __restrict__ bvs,
                                                    unsigned short* __restrict__ xb,
                                                    float* __restrict__ vw) {
    int tid = threadIdx.x, wave = tid >> 6, lane = tid & 63;
    int row = blockIdx.x * 4 + wave;
    size_t base = (size_t)row * DIN_ + lane * 8;
    float4 a = *(const float4*)(x + base);
    float4 b = *(const float4*)(x + base + 4);
    float4 wa = *(const float4*)(wvs + lane * 8);
    float4 wb = *(const float4*)(wvs + lane * 8 + 4);
    uint4 r;
    r.x = f2b(a.x) | ((unsigned)f2b(a.y) << 16);
    r.y = f2b(a.z) | ((unsigned)f2b(a.w) << 16);
    r.z = f2b(b.x) | ((unsigned)f2b(b.y) << 16);
    r.w = f2b(b.z) | ((unsigned)f2b(b.w) << 16);
    *(uint4*)(xb + base) = r;
    float d = a.x * wa.x + a.y * wa.y + a.z * wa.z + a.w * wa.w +
              b.x * wb.x + b.y * wb.y + b.z * wb.z + b.w * wb.w;
    for (int off = 1; off < 64; off <<= 1) d += __shfl_xor(d, off, 64);
    if (lane == 0) vw[row] = d + *bvs;
}

// ---------------- Wq,Wk -> bf16 ----------------
__global__ __launch_bounds__(256) void cvt_w_kernel(const float* __restrict__ wq,
                                                    const float* __restrict__ wk,
                                                    unsigned short* __restrict__ dst) {
    int i = (blockIdx.x * 256 + threadIdx.x) * 8;  // 0 .. 262144-8
    const float* src = (i < 131072) ? (wq + i) : (wk + (i - 131072));
    float4 a = *(const float4*)(src);
    float4 b = *(const float4*)(src + 4);
    uint4 r;
    r.x = f2b(a.x) | ((unsigned)f2b(a.y) << 16);
    r.y = f2b(a.z) | ((unsigned)f2b(a.w) << 16);
    r.z = f2b(b.x) | ((unsigned)f2b(b.y) << 16);
    r.w = f2b(b.z) | ((unsigned)f2b(b.w) << 16);
    *(uint4*)(dst + i) = r;
}

// ---------------- Q,K GEMM ----------------
// grid (128, 8): x = 128-row block (32 rows/wave), y = 64-col block of 512 outputs.
// Each B fragment feeds 2 MFMAs (2 row-frags per wave).
__global__ __launch_bounds__(256, 4) void qkv_kernel(
    const unsigned short* __restrict__ xb, const unsigned short* __restrict__ wb,
    const float* __restrict__ bq, const float* __restrict__ bk,
    unsigned short* __restrict__ q, unsigned short* __restrict__ k) {
    const int tid  = threadIdx.x;
    const int wave = tid >> 6, lane = tid & 63, quad = lane >> 4, l16 = lane & 15;
    const int row0 = blockIdx.x * 128 + wave * 32;
    const int col0 = blockIdx.y * 64;

    floatx4 acc[2][4];
#pragma unroll
    for (int a = 0; a < 2; ++a)
#pragma unroll
        for (int t = 0; t < 4; ++t) acc[a][t] = (floatx4){0.f, 0.f, 0.f, 0.f};

    const unsigned short* arow0 = xb + (size_t)(row0 + l16) * DIN_ + quad * 8;
    const unsigned short* arow1 = xb + (size_t)(row0 + 16 + l16) * DIN_ + quad * 8;
    const unsigned short* brow  = wb + (size_t)(col0 + l16) * DIN_ + quad * 8;
#pragma unroll 2
    for (int kc = 0; kc < DIN_; kc += 32) {
        short8 af0 = *(const short8*)(arow0 + kc);
        short8 af1 = *(const short8*)(arow1 + kc);
#pragma unroll
        for (int ct = 0; ct < 4; ++ct) {
            short8 bf = *(const short8*)(brow + (size_t)ct * 16 * DIN_ + kc);
            acc[0][ct] = __builtin_amdgcn_mfma_f32_16x16x32_bf16(af0, bf, acc[0][ct], 0, 0, 0);
            acc[1][ct] = __builtin_amdgcn_mfma_f32_16x16x32_bf16(af1, bf, acc[1][ct], 0, 0, 0);
        }
    }
#pragma unroll
    for (int ct = 0; ct < 4; ++ct) {
        int col = col0 + ct * 16 + l16;
        unsigned short* dst = (col < 256) ? q : k;
        float bias = (col < 256) ? bq[col] : bk[col - 256];
        int c = col & 255;
#pragma unroll
        for (int a = 0; a < 2; ++a)
#pragma unroll
            for (int r = 0; r < 4; ++r) {
                int row = row0 + a * 16 + quad * 4 + r;
                dst[(size_t)row * DOUT_ + c] = f2b(acc[a][ct][r] + bias);
            }
    }
}

// ---------------- gated flash attention, scalarized V path ----------------
// grid 512: b = g&7 (XCD-affine), rblk = g>>3 -> 32 q-rows.
// 512 threads = 8 waves = 8 m-splits of 256 columns; all waves share the same
// 32 q-rows. Per-lane fixed-max softmax accumulation in fp32; exp2 with log2e
// folded into the gate table. 2 blocks/CU -> 16 waves/CU.
__global__ __launch_bounds__(512, 4) void attn_kernel(
    const unsigned short* __restrict__ q, const unsigned short* __restrict__ k,
    const float* __restrict__ vw, const int* __restrict__ pr,
    const float* __restrict__ rank_emb, const float* __restrict__ rank_w,
    const float* __restrict__ bs, const float* __restrict__ bvs,
    float* __restrict__ out) {
    const int g = blockIdx.x;
    const int b = g & 7, rblk = g >> 3;
    const int tid = threadIdx.x, wave = tid >> 6, lane = tid & 63;
    const int quad = lane >> 4, l16 = lane & 15;
    const int sp = wave;            // m split 0..7
    const int n0 = rblk * 32;

    __shared__ float gtab[NBUCK];
    __shared__ float lL[8][32], wdL[8][32];

    if (tid < NBUCK)  // scale * log2e folded in
        gtab[tid] = 0.0625f * 1.44269504f / (1.f + __expf(-rank_w[0] * rank_emb[tid]));
    __syncthreads();

    const unsigned short* qb = q + (size_t)b * N_ * DOUT_;
    const unsigned short* kb = k + (size_t)b * N_ * DOUT_;
    const float* vwb = vw + b * N_;
    const int* prb = pr + b * N_;

    short8 qf[2][8];
#pragma unroll
    for (int a = 0; a < 2; ++a)
#pragma unroll
        for (int c = 0; c < 8; ++c)
            qf[a][c] = *(const short8*)(qb + (size_t)(n0 + a * 16 + l16) * DOUT_ + c * 32 + quad * 8);

    int prn[2][4];
#pragma unroll
    for (int a = 0; a < 2; ++a)
#pragma unroll
        for (int r = 0; r < 4; ++r) prn[a][r] = prb[n0 + a * 16 + quad * 4 + r];

    float lacc[2][4], wacc[2][4];
#pragma unroll
    for (int a = 0; a < 2; ++a)
#pragma unroll
        for (int r = 0; r < 4; ++r) { lacc[a][r] = 0.f; wacc[a][r] = 0.f; }

    const int mbeg = sp * 256;
    for (int m0 = mbeg; m0 < mbeg + 256; m0 += 32) {
        floatx4 s[2][2];
#pragma unroll
        for (int a = 0; a < 2; ++a)
#pragma unroll
            for (int h = 0; h < 2; ++h) s[a][h] = (floatx4){0.f, 0.f, 0.f, 0.f};
#pragma unroll
        for (int h = 0; h < 2; ++h) {
            const unsigned short* krow = kb + (size_t)(m0 + h * 16 + l16) * DOUT_ + quad * 8;
#pragma unroll
            for (int c = 0; c < 8; ++c) {
                short8 kf = *(const short8*)(krow + c * 32);
                s[0][h] = __builtin_amdgcn_mfma_f32_16x16x32_bf16(qf[0][c], kf, s[0][h], 0, 0, 0);
                s[1][h] = __builtin_amdgcn_mfma_f32_16x16x32_bf16(qf[1][c], kf, s[1][h], 0, 0, 0);
            }
        }
#pragma unroll
        for (int h = 0; h < 2; ++h) {
            int col = m0 + h * 16 + l16;
            int prm = prb[col];
            float vwv = vwb[col];
#pragma unroll
            for (int a = 0; a < 2; ++a)
#pragma unroll
                for (int r = 0; r < 4; ++r) {
                    int d = abs(prn[a][r] - prm);
                    float p = exp2f(s[a][h][r] * gtab[min(d / 5, NBUCK - 1)]);
                    lacc[a][r] += p;
                    wacc[a][r] += p * vwv;
                }
        }
    }

    // merge partial (l, wd) across the 16 column-lanes
#pragma unroll
    for (int off = 1; off < 16; off <<= 1) {
#pragma unroll
        for (int a = 0; a < 2; ++a)
#pragma unroll
            for (int r = 0; r < 4; ++r) {
                lacc[a][r] += __shfl_xor(lacc[a][r], off, 64);
                wacc[a][r] += __shfl_xor(wacc[a][r], off, 64);
            }
    }
    if (l16 == 0) {
#pragma unroll
        for (int a = 0; a < 2; ++a)
#pragma unroll
            for (int r = 0; r < 4; ++r) {
                int row = a * 16 + quad * 4 + r;
                lL[sp][row]  = lacc[a][r];
                wdL[sp][row] = wacc[a][r];
            }
    }
    __syncthreads();
    if (tid < 32) {
        float l = 0.f, wd = 0.f;
#pragma unroll
        for (int s2 = 0; s2 < 8; ++s2) { l += lL[s2][tid]; wd += wdL[s2][tid]; }
        float logit = wd / l + *bvs + bs[0];
        out[(size_t)b * N_ + n0 + tid] = 1.f / (1.f + __expf(-logit));
    }
}

// ---------------- launch ----------------
extern "C" void kernel_launch(void* const* d_in, const int* in_sizes, int n_in,
                              void* d_out, int out_size, void* d_ws, size_t ws_size,
                              hipStream_t stream) {
    const float* x   = (const float*)d_in[0];
    const int*   pr  = (const int*)d_in[1];
    const float* Wq  = (const float*)d_in[2];
    const float* bq  = (const float*)d_in[3];
    const float* Wk  = (const float*)d_in[4];
    const float* bk  = (const float*)d_in[5];
    const float* Wv  = (const float*)d_in[6];
    const float* bv  = (const float*)d_in[7];
    const float* Ws  = (const float*)d_in[8];
    const float* bs  = (const float*)d_in[9];
    const float* remb = (const float*)d_in[10];
    const float* rw   = (const float*)d_in[11];
    float* out = (float*)d_out;

    char* ws = (char*)d_ws;
    unsigned short* xb  = (unsigned short*)ws;                    // 16,777,216 B
    unsigned short* wb  = (unsigned short*)(ws + 16777216);       //    524,288 B
    unsigned short* q   = (unsigned short*)(ws + 17301504);       //  8,388,608 B
    unsigned short* kk  = (unsigned short*)(ws + 25690112);       //  8,388,608 B
    float*          vwp = (float*)(ws + 34078720);                //     65,536 B
    float*          wvs = (float*)(ws + 34144256);                //      2,048 B
    float*          bvs = (float*)(ws + 34146304);                //          4 B

    hipLaunchKernelGGL(wvs_kernel, dim3(4), dim3(128), 0, stream, Wv, Ws, bv, wvs, bvs);
    hipLaunchKernelGGL(cvt_x_kernel, dim3(4096), dim3(256), 0, stream, x, wvs, bvs, xb, vwp);
    hipLaunchKernelGGL(cvt_w_kernel, dim3(128), dim3(256), 0, stream, Wq, Wk, wb);
    hipLaunchKernelGGL(qkv_kernel, dim3(128, 8), dim3(256), 0, stream,
                       xb, wb, bq, bk, q, kk);
    hipLaunchKernelGGL(attn_kernel, dim3(512), dim3(512), 0, stream,
                       q, kk, vwp, pr, remb, rw, bs, bvs, out);
}